// Round 2
// baseline (686.365 us; speedup 1.0000x reference)
//
#include <hip/hip_runtime.h>
#include <math.h>

// PrototypicalLoss: B=8192, N=64, D=256 fp32.
// THIS ROUND: kill ALL data-dependent control flow. The label-skip while(mm)
// loop capped streaming at ~0.9 TB/s (invariant to 1-deep vs 8-deep MLP ->
// compiler can't pipeline across data-dependent iteration boundaries).
// New shape: one BLOCK per b; wave w streams rows [16w,16w+16) = 16 KiB
// CONTIGUOUS with a static fully-unrolled trip count and 0/1 weights.
// Reads 100% of support (522 MB, floor 83 us) but at streaming efficiency.

__global__ __launch_bounds__(256) void proto_dist_kernel(
    const float* __restrict__ query,    // (B, 256)
    const float* __restrict__ support,  // (B, 64, 256)
    const int*   __restrict__ labels,   // (B, 64)
    float* __restrict__ dists,          // (B,)
    int B)
{
    const int lane = threadIdx.x & 63;
    const int wv   = threadIdx.x >> 6;   // 4 waves per block
    const int b    = blockIdx.x;
    if (b >= B) return;

    __shared__ float4 part[4][64];

    // Every wave loads all 64 labels (256 B, L1-shared) -> uniform 64-bit mask.
    const int lab = labels[(size_t)b * 64 + lane];
    const unsigned long long m = __ballot(lab == 1);
    const int count = __popcll(m);

    const float4* srow = (const float4*)(support + (size_t)b * 64 * 256);

    // Wave 0 also pulls the query row early (overlaps the streaming loop).
    float4 q = make_float4(0.f, 0.f, 0.f, 0.f);
    if (wv == 0)
        q = ((const float4*)(query + (size_t)b * 256))[lane];

    // --- static streaming loop: 16 consecutive rows per wave ---
    const int r0 = wv * 16;
    float4 acc = make_float4(0.f, 0.f, 0.f, 0.f);
    #pragma unroll
    for (int j = 0; j < 16; ++j) {
        const float  w = ((m >> (unsigned)(r0 + j)) & 1ULL) ? 1.0f : 0.0f;
        const float4 v = srow[(size_t)(r0 + j) * 64 + lane];
        acc.x = fmaf(w, v.x, acc.x);
        acc.y = fmaf(w, v.y, acc.y);
        acc.z = fmaf(w, v.z, acc.z);
        acc.w = fmaf(w, v.w, acc.w);
    }
    part[wv][lane] = acc;
    __syncthreads();

    if (wv == 0) {
        const float4 s0 = part[0][lane];
        const float4 s1 = part[1][lane];
        const float4 s2 = part[2][lane];
        const float4 s3 = part[3][lane];
        float4 sum = make_float4(s0.x + s1.x + s2.x + s3.x,
                                 s0.y + s1.y + s2.y + s3.y,
                                 s0.z + s1.z + s2.z + s3.z,
                                 s0.w + s1.w + s2.w + s3.w);
        float4 proto;
        if (count > 0) {                 // wave-uniform branch
            const float inv = 1.0f / (float)count;
            proto = make_float4(sum.x * inv, sum.y * inv, sum.z * inv, sum.w * inv);
        } else {
            proto = srow[lane];          // fallback: support[b, 0, :] (L1/L2 hit)
        }

        const float dx = q.x - proto.x;
        const float dy = q.y - proto.y;
        const float dz = q.z - proto.z;
        const float dw = q.w - proto.w;
        float ss = dx * dx + dy * dy + dz * dz + dw * dw;

        #pragma unroll
        for (int off = 32; off > 0; off >>= 1)
            ss += __shfl_down(ss, off, 64);

        if (lane == 0)
            dists[b] = sqrtf(ss + 1e-8f);
    }
}

__global__ __launch_bounds__(256) void reduce_mean_kernel(
    const float* __restrict__ dists, float* __restrict__ out, int B)
{
    __shared__ float sm[4];
    float s = 0.f;
    for (int i = threadIdx.x; i < B; i += 256)
        s += dists[i];
    #pragma unroll
    for (int off = 32; off > 0; off >>= 1)
        s += __shfl_down(s, off, 64);
    const int lane = threadIdx.x & 63;
    const int wv   = threadIdx.x >> 6;
    if (lane == 0) sm[wv] = s;
    __syncthreads();
    if (threadIdx.x == 0)
        out[0] = (sm[0] + sm[1] + sm[2] + sm[3]) / (float)B;
}

extern "C" void kernel_launch(void* const* d_in, const int* in_sizes, int n_in,
                              void* d_out, int out_size, void* d_ws, size_t ws_size,
                              hipStream_t stream) {
    const float* query   = (const float*)d_in[0];   // (B, D) fp32
    const float* support = (const float*)d_in[1];   // (B, N, D) fp32
    const int*   labels  = (const int*)d_in[2];     // (B, N) int32
    float* out = (float*)d_out;

    const int n_q = in_sizes[0];
    const int n_s = in_sizes[1];
    const int n_l = in_sizes[2];
    const int D = n_s / n_l;        // 256
    const int B = n_q / D;          // 8192
    (void)n_in; (void)out_size; (void)ws_size;

    float* dists = (float*)d_ws;    // B floats of scratch

    proto_dist_kernel<<<B, 256, 0, stream>>>(query, support, labels, dists, B);
    reduce_mean_kernel<<<1, 256, 0, stream>>>(dists, out, B);
}

// Round 3
// 635.205 us; speedup vs baseline: 1.0805x; 1.0805x over previous
//
#include <hip/hip_runtime.h>
#include <math.h>

// PrototypicalLoss: B=8192, N=64, D=256 fp32.
// One wave (64 lanes) per batch element. Lane l owns floats [4l, 4l+4) of D.
// Label-skip: only support rows with label==1 are read (~50% of 512 MiB),
// each as a fully-coalesced 1 KiB row. R1<->R2 A/B established the load
// stream runs at ~5.4-6 TB/s marginal BW, so ~266 MB minimum traffic
// (~43 us) is the kernel-side roofline; total is harness-fill dominated.

__global__ __launch_bounds__(256) void proto_dist_kernel(
    const float* __restrict__ query,    // (B, 256)
    const float* __restrict__ support,  // (B, 64, 256)
    const int*   __restrict__ labels,   // (B, 64)
    float* __restrict__ dists,          // (B,)
    int B)
{
    const int lane = threadIdx.x & 63;
    const int wv   = threadIdx.x >> 6;
    const int b    = blockIdx.x * 4 + wv;
    if (b >= B) return;

    // Load query early so it overlaps the support streaming.
    const float4 q = ((const float4*)(query + (size_t)b * 256))[lane];

    // one label per lane -> wave-uniform 64-bit mask (SGPR pair)
    const int lab = labels[(size_t)b * 64 + lane];
    const unsigned long long m = __ballot(lab == 1);
    const int count = __popcll(m);

    // support rows for this b, viewed as 64 float4 per row
    const float4* srow = (const float4*)(support + (size_t)b * 64 * 256);

    float4 acc = make_float4(0.f, 0.f, 0.f, 0.f);
    unsigned long long mm = m;
    while (mm) {                        // wave-uniform loop
        // --- extract up to 8 set-bit row indices, branch-free scalar ops ---
        int   n[8];
        float w[8];
        n[0] = __builtin_ctzll(mm);     // while-cond guarantees a bit
        w[0] = 1.0f;
        mm &= (mm - 1ULL);
        #pragma unroll
        for (int j = 1; j < 8; ++j) {
            const bool has = (mm != 0ULL);
            n[j] = has ? __builtin_ctzll(mm) : n[0];  // pad with dup of n[0] (L1 hit)
            w[j] = has ? 1.0f : 0.0f;
            mm   = has ? (mm & (mm - 1ULL)) : 0ULL;
        }
        // --- issue all 8 independent loads before any use ---
        float4 v[8];
        #pragma unroll
        for (int j = 0; j < 8; ++j)
            v[j] = srow[(size_t)n[j] * 64 + lane];
        // --- weighted accumulate (w=0 kills the pad duplicates) ---
        #pragma unroll
        for (int j = 0; j < 8; ++j) {
            acc.x = fmaf(w[j], v[j].x, acc.x);
            acc.y = fmaf(w[j], v[j].y, acc.y);
            acc.z = fmaf(w[j], v[j].z, acc.z);
            acc.w = fmaf(w[j], v[j].w, acc.w);
        }
    }

    float4 proto;
    if (count > 0) {                    // wave-uniform branch
        const float inv = 1.0f / (float)count;
        proto = make_float4(acc.x * inv, acc.y * inv, acc.z * inv, acc.w * inv);
    } else {
        proto = srow[lane];             // fallback: support[b, 0, :]
    }

    const float dx = q.x - proto.x;
    const float dy = q.y - proto.y;
    const float dz = q.z - proto.z;
    const float dw = q.w - proto.w;
    float ss = dx * dx + dy * dy + dz * dz + dw * dw;

    // reduce across the 64-lane wave
    #pragma unroll
    for (int off = 32; off > 0; off >>= 1)
        ss += __shfl_down(ss, off, 64);

    if (lane == 0)
        dists[b] = sqrtf(ss + 1e-8f);
}

// Final mean over B dists. One block; each thread pulls 8 independent float4
// (B=8192 -> 2048 float4 -> 256 threads x 8) so the tail kernel is
// latency-pipelined instead of 32 serial scalar loads.
__global__ __launch_bounds__(256) void reduce_mean_kernel(
    const float* __restrict__ dists, float* __restrict__ out, int B)
{
    __shared__ float sm[4];
    const float4* d4 = (const float4*)dists;
    const int nv = B / 4;               // 2048 float4
    float s = 0.f;
    #pragma unroll
    for (int j = 0; j < 8; ++j) {
        const int i = threadIdx.x + j * 256;
        if (i < nv) {
            const float4 v = d4[i];
            s += (v.x + v.y) + (v.z + v.w);
        }
    }
    #pragma unroll
    for (int off = 32; off > 0; off >>= 1)
        s += __shfl_down(s, off, 64);
    const int lane = threadIdx.x & 63;
    const int wv   = threadIdx.x >> 6;
    if (lane == 0) sm[wv] = s;
    __syncthreads();
    if (threadIdx.x == 0)
        out[0] = (sm[0] + sm[1] + sm[2] + sm[3]) / (float)B;
}

extern "C" void kernel_launch(void* const* d_in, const int* in_sizes, int n_in,
                              void* d_out, int out_size, void* d_ws, size_t ws_size,
                              hipStream_t stream) {
    const float* query   = (const float*)d_in[0];   // (B, D) fp32
    const float* support = (const float*)d_in[1];   // (B, N, D) fp32
    const int*   labels  = (const int*)d_in[2];     // (B, N) int32
    float* out = (float*)d_out;

    const int n_q = in_sizes[0];
    const int n_s = in_sizes[1];
    const int n_l = in_sizes[2];
    const int D = n_s / n_l;        // 256
    const int B = n_q / D;          // 8192
    (void)n_in; (void)out_size; (void)ws_size;

    float* dists = (float*)d_ws;    // B floats of scratch

    const int blocks = (B + 3) / 4; // 4 waves (batch elems) per 256-thread block
    proto_dist_kernel<<<blocks, 256, 0, stream>>>(query, support, labels, dists, B);
    reduce_mean_kernel<<<1, 256, 0, stream>>>(dists, out, B);
}